// Round 5
// baseline (241.839 us; speedup 1.0000x reference)
//
#include <hip/hip_runtime.h>

// RoPEAttentionHead: x[256,16,2048], w_q/w_k/w_v [2048,2048] -> out [256,16,2048]
// Stage 0: (f32 only) convert inputs -> bf16 in ws
// Stage 1: fused QKV GEMM (C = X @ W^T, N fused over q/k/v = 6144) + rotary epilogue
//          128x192 tile, BK=64, 4 waves (each 64x96), double-buffered 80 KiB LDS
//          (2 blocks/CU). K-loop: 2 pipelined half-phases per tile -- ds_reads of
//          the NEXT half issued before each 24-MFMA cluster (T3 fine interleave),
//          counted prefetch depth ~1.5 tiles (T4), XOR-swizzled LDS (T2), setprio (T5).
// Stage 2: per-batch 16x16 attention, 512 threads (8-way K-split QK^T, 4-col PV)

#define D 2048
#define SEQLEN 16
#define NBATCH 256
#define NROWS (NBATCH * SEQLEN)   // 4096
#define NX (NROWS * D)            // 8388608
#define NW (D * D)                // 4194304

#define BM 128
#define BN 192
#define BK 64
#define NKT (D / BK)              // 32 K-tiles
#define LDSPB ((BM + BN) * BK)    // 20480 ushorts per buffer (40960 B); x2 = 80 KiB

typedef __attribute__((ext_vector_type(8))) short bf16x8;   // 8 bf16 = 4 VGPRs
typedef __attribute__((ext_vector_type(4))) float f32x4;

__device__ __forceinline__ unsigned short f32_to_bf16(float f) {
  unsigned u = __float_as_uint(f);
  unsigned r = 0x7fffu + ((u >> 16) & 1u);   // RNE
  return (unsigned short)((u + r) >> 16);
}
__device__ __forceinline__ float bf16lo_to_f32(unsigned u) { return __uint_as_float(u << 16); }
__device__ __forceinline__ float bf16hi_to_f32(unsigned u) { return __uint_as_float(u & 0xffff0000u); }

// True if `w` holds float32 data (reading it as bf16 gives wild exponents).
__device__ __forceinline__ bool detect_f32(const ushort* __restrict__ w) {
  int crazy = 0;
#pragma unroll
  for (int i = 0; i < 64; ++i) {
    float v = __uint_as_float((unsigned)w[i] << 16);
    if (!(__builtin_fabsf(v) < 256.0f)) ++crazy;
  }
  return crazy >= 3;
}

__device__ __forceinline__ void glds16(const void* g, void* l) {
  __builtin_amdgcn_global_load_lds(
      (const __attribute__((address_space(1))) void*)g,
      (__attribute__((address_space(3))) void*)l, 16, 0, 0);
}

// ---------------- Stage 0: f32 -> bf16 conversion (no-op for bf16 inputs) ----------------
__global__ __launch_bounds__(256) void convert_inputs(
    const void* __restrict__ x, const void* __restrict__ wq,
    const void* __restrict__ wk, const void* __restrict__ wv,
    ushort* __restrict__ xb, ushort* __restrict__ wqb,
    ushort* __restrict__ wkb, ushort* __restrict__ wvb) {
  if (!detect_f32((const ushort*)wq)) return;
  const float* srcs[4] = {(const float*)x, (const float*)wq, (const float*)wk, (const float*)wv};
  ushort* dsts[4] = {xb, wqb, wkb, wvb};
  const int ns[4] = {NX, NW, NW, NW};
  const int stride = gridDim.x * blockDim.x;
#pragma unroll
  for (int s = 0; s < 4; ++s) {
    const float* __restrict__ src = srcs[s];
    ushort* __restrict__ dst = dsts[s];
    const int n8 = ns[s] / 8;
    for (int i = blockIdx.x * blockDim.x + threadIdx.x; i < n8; i += stride) {
      float4 a = ((const float4*)src)[i * 2];
      float4 b = ((const float4*)src)[i * 2 + 1];
      uint4 o;
      o.x = (unsigned)f32_to_bf16(a.x) | ((unsigned)f32_to_bf16(a.y) << 16);
      o.y = (unsigned)f32_to_bf16(a.z) | ((unsigned)f32_to_bf16(a.w) << 16);
      o.z = (unsigned)f32_to_bf16(b.x) | ((unsigned)f32_to_bf16(b.y) << 16);
      o.w = (unsigned)f32_to_bf16(b.z) | ((unsigned)f32_to_bf16(b.w) << 16);
      ((uint4*)dst)[i] = o;
    }
  }
}

// ---------------- Stage 1: fused QKV GEMM (N=6144) + rotary ----------------
// grid 1024 = (M/128=32) x (N/192=32), block 256 (4 waves 2x2; per wave 64x96).
// LDS 80 KiB -> 2 blocks/CU resident.
__global__ __launch_bounds__(256, 2) void qkv_rope_gemm(
    const void* __restrict__ Xr, const void* __restrict__ Wqr,
    const void* __restrict__ Wkr, const void* __restrict__ Wvr,
    const ushort* __restrict__ xb, const ushort* __restrict__ wqb,
    const ushort* __restrict__ wkb, const ushort* __restrict__ wvb,
    ushort* __restrict__ Oq, ushort* __restrict__ Ok, ushort* __restrict__ Ov) {
  __shared__ __align__(16) ushort lds[2][LDSPB];   // [buf][A 128x64 | B 192x64]

  const bool f32in = detect_f32((const ushort*)Wqr);
  const ushort* __restrict__ X  = f32in ? xb  : (const ushort*)Xr;
  const ushort* __restrict__ Wq = f32in ? wqb : (const ushort*)Wqr;
  const ushort* __restrict__ Wk = f32in ? wkb : (const ushort*)Wkr;
  const ushort* __restrict__ Wv = f32in ? wvb : (const ushort*)Wvr;

  // n-major within an m-panel: consecutive blocks share the X panel in L2.
  const int m0 = (blockIdx.x >> 5) * BM;
  const int n0 = (blockIdx.x & 31) * BN;

  const int t = threadIdx.x;
  const int wave = t >> 6, lane = t & 63;
  const int quad = lane >> 4, l16 = lane & 15;
  const int wr = wave >> 1, wc = wave & 1;      // 2 x 2 wave grid, per-wave 64x96

  // Staging: linear LDS dest (global_load_lds requirement), PRE-SWIZZLED global source.
  // LDS element (row, slot s) holds global k-slot s ^ (row&7); reads XOR the same way.
  // 256 threads cover 32 rows x 64 cols (1 chunk) per glds round; A=4 chunks, B=6.
  const int srow = t >> 3;                        // 0..31 (row within 32-row chunk)
  const int scol = ((t & 7) ^ (srow & 7)) * 8;    // pre-swizzled element offset
  const ushort* gA = X + (size_t)(m0 + srow) * D + scol;
  const ushort* gB[6];
#pragma unroll
  for (int c = 0; c < 6; ++c) {
    const int ng = n0 + c * 32 + srow;            // 32-row chunks never straddle z
    const int z = ng >> 11;
    gB[c] = ((z == 0) ? Wq : (z == 1) ? Wk : Wv) + (size_t)(ng & 2047) * D + scol;
  }

  f32x4 acc[4][6] = {};

  auto STAGE = [&](int b, int kt) {
    const int kc = kt * BK;
#pragma unroll
    for (int c = 0; c < 4; ++c)                   // A rows c*32 .. c*32+31
      glds16(gA + (size_t)c * 32 * D + kc, &lds[b][c * 2048 + t * 8]);
#pragma unroll
    for (int c = 0; c < 6; ++c)                   // B rows c*32 .. c*32+31
      glds16(gB[c] + kc, &lds[b][BM * BK + c * 2048 + t * 8]);
  };

  const int swz = (l16 & 7) << 3;                 // T2 swizzle (row&7 == l16&7)

  // Half-tile fragment readers (ks = 0/1 selects the 32-wide K half).
  auto RD = [&](int buf, int ks, bf16x8* af, bf16x8* bfr) {
    const ushort* Ab = &lds[buf][0];
    const ushort* Bb = &lds[buf][BM * BK];
    const int ko = (ks * 32 + quad * 8) ^ swz;
#pragma unroll
    for (int f = 0; f < 4; ++f)
      af[f] = *(const bf16x8*)(Ab + (wr * 64 + f * 16 + l16) * 64 + ko);
#pragma unroll
    for (int g = 0; g < 6; ++g)
      bfr[g] = *(const bf16x8*)(Bb + (wc * 96 + g * 16 + l16) * 64 + ko);
  };

  // Prologue: fill both buffers (depth-2 pipeline), wait tile 0 only, pre-read ks0.
  STAGE(0, 0);
  STAGE(1, 1);
  asm volatile("s_waitcnt vmcnt(10)" ::: "memory");   // tile 0 landed; tile 1 in flight
  __builtin_amdgcn_s_barrier();
  __builtin_amdgcn_sched_barrier(0);

  bf16x8 a0[4], b0[6], a1[4], b1[6];
  RD(0, 0, a0, b0);                                   // tile 0, ks0 (compiler waits at use)

  for (int kt = 0; kt < NKT; ++kt) {
    const int cur = kt & 1;

    // ---- P1: issue ks1 reads, then MFMA ks0 (reads service under the cluster) ----
    RD(cur, 1, a1, b1);
    __builtin_amdgcn_s_barrier();                     // phase align
    __builtin_amdgcn_sched_barrier(0);                // pin reads before this cluster
    __builtin_amdgcn_s_setprio(1);
#pragma unroll
    for (int f = 0; f < 4; ++f)
#pragma unroll
      for (int g = 0; g < 6; ++g)
        acc[f][g] = __builtin_amdgcn_mfma_f32_16x16x32_bf16(a0[f], b0[g], acc[f][g], 0, 0, 0);
    __builtin_amdgcn_s_setprio(0);

    // ---- P2: buffer handoff, issue next-tile ks0 reads + STAGE, MFMA ks1 ----
    asm volatile("s_waitcnt lgkmcnt(0)" ::: "memory");   // my reads of buf[cur] all done
    if (kt + 1 < NKT)
      asm volatile("s_waitcnt vmcnt(0)" ::: "memory");   // tile kt+1 glds (1 tile old) landed
    __builtin_amdgcn_s_barrier();                        // all waves done with buf[cur];
    __builtin_amdgcn_sched_barrier(0);                   // buf[cur^1] ready CU-wide
    if (kt + 1 < NKT) RD(cur ^ 1, 0, a0, b0);            // next tile ks0
    if (kt + 2 < NKT) STAGE(cur, kt + 2);                // refill the buffer just freed
    __builtin_amdgcn_sched_barrier(0);                   // pin reads/glds before cluster
    __builtin_amdgcn_s_setprio(1);
#pragma unroll
    for (int f = 0; f < 4; ++f)
#pragma unroll
      for (int g = 0; g < 6; ++g)
        acc[f][g] = __builtin_amdgcn_mfma_f32_16x16x32_bf16(a1[f], b1[g], acc[f][g], 0, 0, 0);
    __builtin_amdgcn_s_setprio(0);
  }

  // Epilogue: rotary (z<2) + bf16 store.
  // C layout per fragment: col = l16 (e), row = quad*4 + r; seq pos = row & 15.
#pragma unroll
  for (int g = 0; g < 6; ++g) {
    const int eg = n0 + wc * 96 + g * 16 + l16;   // 16-col groups never cross z
    const int z = eg >> 11;
    const int e = eg & 2047;
    const bool rope = (z != 2);
    ushort* __restrict__ O = (z == 0) ? Oq : (z == 1) ? Ok : Ov;
    float cs[4] = {}, sn[4] = {};
    if (rope) {
      // theta = 10000^(-2*(i-1)/2048), i = e>>1  (keeps the reference's i-1 "bug")
      const float theta = exp2f(-0.012976281620653759f * ((float)(e >> 1) - 1.0f));
#pragma unroll
      for (int r = 0; r < 4; ++r)
        __sincosf((float)(quad * 4 + r) * theta, &sn[r], &cs[r]);
    }
#pragma unroll
    for (int f = 0; f < 4; ++f) {
      const size_t rbase = (size_t)(m0 + wr * 64 + f * 16 + quad * 4) * D;
#pragma unroll
      for (int r = 0; r < 4; ++r) {
        float v = acc[f][g][r];
        float p = __shfl_xor(v, 1);          // partner along e (pair 2i / 2i+1)
        float o = v;
        if (rope)
          o = (e & 1) ? (v * cs[r] - p * sn[r])    // odd:  -q[2i]*sin + q[2i+1]*cos
                      : (v * cs[r] + p * sn[r]);   // even:  q[2i]*cos + q[2i+1]*sin
        O[rbase + (size_t)r * D + e] = f32_to_bf16(o);
      }
    }
  }
}

// ---------------- Stage 2: attention ----------------
// grid 256 (one block per batch), block 512.
// scores = q_rot @ k_rot^T via 16x16x32 MFMA, K=2048 split 8 ways across waves.
__global__ __launch_bounds__(512) void rope_attention(
    const ushort* __restrict__ Q, const ushort* __restrict__ K,
    const ushort* __restrict__ V, const void* __restrict__ Wqr, void* __restrict__ OutRaw) {
  __shared__ float sc[8][16][16];
  __shared__ float at[16][16];
  const bool f32out = detect_f32((const ushort*)Wqr);
  const int b = blockIdx.x;
  const int t = threadIdx.x;
  const int wave = t >> 6, lane = t & 63;
  const int quad = lane >> 4, l16 = lane & 15;

  const ushort* Qb = Q + (size_t)b * (SEQLEN * D);
  const ushort* Kb = K + (size_t)b * (SEQLEN * D);

  f32x4 acc = {0.f, 0.f, 0.f, 0.f};
  const ushort* qp = Qb + l16 * D + wave * 256 + quad * 8;
  const ushort* kp = Kb + l16 * D + wave * 256 + quad * 8;
#pragma unroll
  for (int s = 0; s < 8; ++s) {
    bf16x8 a = *(const bf16x8*)(qp + s * 32);
    bf16x8 bb = *(const bf16x8*)(kp + s * 32);
    acc = __builtin_amdgcn_mfma_f32_16x16x32_bf16(a, bb, acc, 0, 0, 0);
  }
#pragma unroll
  for (int r = 0; r < 4; ++r)
    sc[wave][quad * 4 + r][l16] = acc[r];
  __syncthreads();

  if (t < 256) {
    const int m = t >> 4, n = t & 15;
    float s = (sc[0][m][n] + sc[1][m][n] + sc[2][m][n] + sc[3][m][n] +
               sc[4][m][n] + sc[5][m][n] + sc[6][m][n] + sc[7][m][n]) * 0.02209708691207961f;
    float mx = s;
#pragma unroll
    for (int off = 8; off; off >>= 1) mx = fmaxf(mx, __shfl_xor(mx, off, 16));
    float e = __expf(s - mx);
    float sum = e;
#pragma unroll
    for (int off = 8; off; off >>= 1) sum += __shfl_xor(sum, off, 16);
    at[m][n] = e / sum;
  }
  __syncthreads();

  // PV: thread t owns 4 contiguous e-cols; v held in regs as packed bf16.
  const ushort* Vb = V + (size_t)b * (SEQLEN * D);
  const int e0 = t * 4;
  uint2 vr[16];
#pragma unroll
  for (int n = 0; n < 16; ++n)
    vr[n] = *(const uint2*)(Vb + n * D + e0);

  for (int m = 0; m < 16; ++m) {
    float av[4] = {0.f, 0.f, 0.f, 0.f};
#pragma unroll
    for (int n = 0; n < 16; ++n) {
      const float a = at[m][n];
      const uint2 u = vr[n];
      av[0] = fmaf(a, bf16lo_to_f32(u.x), av[0]);
      av[1] = fmaf(a, bf16hi_to_f32(u.x), av[1]);
      av[2] = fmaf(a, bf16lo_to_f32(u.y), av[2]);
      av[3] = fmaf(a, bf16hi_to_f32(u.y), av[3]);
    }
    if (f32out) {
      float* Ob = (float*)OutRaw + (size_t)b * (SEQLEN * D) + m * D + e0;
      float4 o0 = {av[0], av[1], av[2], av[3]};
      *(float4*)Ob = o0;
    } else {
      uint2 o;
      o.x = (unsigned)f32_to_bf16(av[0]) | ((unsigned)f32_to_bf16(av[1]) << 16);
      o.y = (unsigned)f32_to_bf16(av[2]) | ((unsigned)f32_to_bf16(av[3]) << 16);
      *(uint2*)((ushort*)OutRaw + (size_t)b * (SEQLEN * D) + m * D + e0) = o;
    }
  }
}

extern "C" void kernel_launch(void* const* d_in, const int* in_sizes, int n_in,
                              void* d_out, int out_size, void* d_ws, size_t ws_size,
                              hipStream_t stream) {
  const void* x  = d_in[0];
  const void* wq = d_in[1];
  const void* wk = d_in[2];
  const void* wv = d_in[3];
  ushort* ws = (ushort*)d_ws;
  ushort* xb  = ws;
  ushort* wqb = ws + NX;
  ushort* wkb = ws + NX + NW;
  ushort* wvb = ws + NX + 2 * (size_t)NW;
  ushort* q = ws + NX + 3 * (size_t)NW;
  ushort* k = q + NX;
  ushort* v = k + NX;

  convert_inputs<<<1536, 256, 0, stream>>>(x, wq, wk, wv, xb, wqb, wkb, wvb);
  qkv_rope_gemm<<<dim3(1024), 256, 0, stream>>>(x, wq, wk, wv, xb, wqb, wkb, wvb, q, k, v);
  rope_attention<<<NBATCH, 512, 0, stream>>>(q, k, v, wq, (ushort*)d_out);
}

// Round 7
// 226.076 us; speedup vs baseline: 1.0697x; 1.0697x over previous
//
#include <hip/hip_runtime.h>

// RoPEAttentionHead: x[256,16,2048], w_q/w_k/w_v [2048,2048] -> out [256,16,2048]
// Stage 0: (f32 only) convert inputs -> bf16 in ws
// Stage 1: fused QKV GEMM + rotary + PARTIAL SCORES. Each block owns e-slice
//          [e0,e0+64) of q,k,v for 128 rows (8 batches): 128x192 tile, BK=64,
//          4 waves, double-buffered 80 KiB LDS (2 blocks/CU), round-4 schedule
//          (counted vmcnt(10) depth-2 prefetch, single-phase K-tile, T2 swizzle,
//          setprio). Epilogue: rope in regs; v -> HBM; q_rot/k_rot -> reused LDS;
//          per-batch S_partial = q_rot @ k_rot^T (K=64) -> Sp[eb][b][16][16].
//          q,k never round-trip through HBM.
// Stage 2: per-batch: sum 32 e-slice partials -> softmax -> P@V (VALU) -> out.

#define D 2048
#define SEQLEN 16
#define NBATCH 256
#define NROWS (NBATCH * SEQLEN)   // 4096
#define NX (NROWS * D)            // 8388608
#define NW (D * D)                // 4194304

#define BM 128
#define BN 192
#define BK 64
#define NKT (D / BK)              // 32 K-tiles
#define LDSPB ((BM + BN) * BK)    // 20480 ushorts per buffer (40960 B); x2 = 80 KiB

typedef __attribute__((ext_vector_type(8))) short bf16x8;   // 8 bf16 = 4 VGPRs
typedef __attribute__((ext_vector_type(4))) float f32x4;

__device__ __forceinline__ unsigned short f32_to_bf16(float f) {
  unsigned u = __float_as_uint(f);
  unsigned r = 0x7fffu + ((u >> 16) & 1u);   // RNE
  return (unsigned short)((u + r) >> 16);
}
__device__ __forceinline__ float bf16lo_to_f32(unsigned u) { return __uint_as_float(u << 16); }
__device__ __forceinline__ float bf16hi_to_f32(unsigned u) { return __uint_as_float(u & 0xffff0000u); }

// True if `w` holds float32 data (reading it as bf16 gives wild exponents).
__device__ __forceinline__ bool detect_f32(const ushort* __restrict__ w) {
  int crazy = 0;
#pragma unroll
  for (int i = 0; i < 64; ++i) {
    float v = __uint_as_float((unsigned)w[i] << 16);
    if (!(__builtin_fabsf(v) < 256.0f)) ++crazy;
  }
  return crazy >= 3;
}

__device__ __forceinline__ void glds16(const void* g, void* l) {
  __builtin_amdgcn_global_load_lds(
      (const __attribute__((address_space(1))) void*)g,
      (__attribute__((address_space(3))) void*)l, 16, 0, 0);
}

// ---------------- Stage 0: f32 -> bf16 conversion (no-op for bf16 inputs) ----------------
__global__ __launch_bounds__(256) void convert_inputs(
    const void* __restrict__ x, const void* __restrict__ wq,
    const void* __restrict__ wk, const void* __restrict__ wv,
    ushort* __restrict__ xb, ushort* __restrict__ wqb,
    ushort* __restrict__ wkb, ushort* __restrict__ wvb) {
  if (!detect_f32((const ushort*)wq)) return;
  const float* srcs[4] = {(const float*)x, (const float*)wq, (const float*)wk, (const float*)wv};
  ushort* dsts[4] = {xb, wqb, wkb, wvb};
  const int ns[4] = {NX, NW, NW, NW};
  const int stride = gridDim.x * blockDim.x;
#pragma unroll
  for (int s = 0; s < 4; ++s) {
    const float* __restrict__ src = srcs[s];
    ushort* __restrict__ dst = dsts[s];
    const int n8 = ns[s] / 8;
    for (int i = blockIdx.x * blockDim.x + threadIdx.x; i < n8; i += stride) {
      float4 a = ((const float4*)src)[i * 2];
      float4 b = ((const float4*)src)[i * 2 + 1];
      uint4 o;
      o.x = (unsigned)f32_to_bf16(a.x) | ((unsigned)f32_to_bf16(a.y) << 16);
      o.y = (unsigned)f32_to_bf16(a.z) | ((unsigned)f32_to_bf16(a.w) << 16);
      o.z = (unsigned)f32_to_bf16(b.x) | ((unsigned)f32_to_bf16(b.y) << 16);
      o.w = (unsigned)f32_to_bf16(b.z) | ((unsigned)f32_to_bf16(b.w) << 16);
      ((uint4*)dst)[i] = o;
    }
  }
}

// ---------------- Stage 1: fused QKV GEMM + rotary + partial scores ----------------
// grid 1024 = (M/128=32) x (e/64=32), block 256 (4 waves 2x2; per wave 64x96).
// Fused-N rows 0..191 = {q,k,v} x e-slice [e0, e0+64).
__global__ __launch_bounds__(256, 2) void qkv_rope_gemm(
    const void* __restrict__ Xr, const void* __restrict__ Wqr,
    const void* __restrict__ Wkr, const void* __restrict__ Wvr,
    const ushort* __restrict__ xb, const ushort* __restrict__ wqb,
    const ushort* __restrict__ wkb, const ushort* __restrict__ wvb,
    ushort* __restrict__ Ov, float* __restrict__ Sp) {
  __shared__ __align__(16) ushort lds[2][LDSPB];   // [buf][A 128x64 | B 192x64]

  const bool f32in = detect_f32((const ushort*)Wqr);
  const ushort* __restrict__ X  = f32in ? xb  : (const ushort*)Xr;
  const ushort* __restrict__ Wq = f32in ? wqb : (const ushort*)Wqr;
  const ushort* __restrict__ Wk = f32in ? wkb : (const ushort*)Wkr;
  const ushort* __restrict__ Wv = f32in ? wvb : (const ushort*)Wvr;

  // e-major within an m-panel: consecutive blocks share the X panel in L2.
  const int m0 = (blockIdx.x >> 5) * BM;
  const int eb = blockIdx.x & 31;
  const int e0 = eb * 64;

  const int t = threadIdx.x;
  const int wave = t >> 6, lane = t & 63;
  const int quad = lane >> 4, l16 = lane & 15;
  const int wr = wave >> 1, wc = wave & 1;      // 2 x 2 wave grid, per-wave 64x96

  // Staging: linear LDS dest (global_load_lds requirement), PRE-SWIZZLED global source.
  // LDS element (row, slot s) holds global k-slot s ^ (row&7); reads XOR the same way.
  const int srow = t >> 3;                        // 0..31 (row within 32-row chunk)
  const int scol = ((t & 7) ^ (srow & 7)) * 8;    // pre-swizzled element offset
  const ushort* gA = X + (size_t)(m0 + srow) * D + scol;
  const ushort* gB[6];
#pragma unroll
  for (int c = 0; c < 6; ++c) {
    // fused rows 32c..32c+31: z = c>>1 (0=q,1=k,2=v); W-row = e0 + (c&1)*32 + srow
    const ushort* Wz = (c < 2) ? Wq : (c < 4) ? Wk : Wv;
    gB[c] = Wz + (size_t)(e0 + (c & 1) * 32 + srow) * D + scol;
  }

  f32x4 acc[4][6] = {};

  auto STAGE = [&](int b, int kt) {
    const int kc = kt * BK;
#pragma unroll
    for (int c = 0; c < 4; ++c)                   // A rows c*32 .. c*32+31
      glds16(gA + (size_t)c * 32 * D + kc, &lds[b][c * 2048 + t * 8]);
#pragma unroll
    for (int c = 0; c < 6; ++c)                   // B fused rows c*32 .. c*32+31
      glds16(gB[c] + kc, &lds[b][BM * BK + c * 2048 + t * 8]);
  };

  // Prologue: fill both buffers (depth-2 pipeline; 20 glds in flight).
  STAGE(0, 0);
  STAGE(1, 1);

  const int swz = (l16 & 7) << 3;                 // T2 swizzle (row&7 == l16&7)

  for (int kt = 0; kt < NKT; ++kt) {
    const int cur = kt & 1;

    // Counted wait (T4): allow the newest STAGE's 10 glds to stay in flight;
    // FIFO retirement => all older loads (incl. tile kt's) have landed.
    if (kt < NKT - 1) asm volatile("s_waitcnt vmcnt(10)" ::: "memory");
    else              asm volatile("s_waitcnt vmcnt(0)"  ::: "memory");
    __builtin_amdgcn_s_barrier();                 // tile kt ready CU-wide
    __builtin_amdgcn_sched_barrier(0);            // no reads above this point

    const ushort* Ab = &lds[cur][0];
    const ushort* Bb = &lds[cur][BM * BK];

    // Single phase: all 20 fragment reads for the full K-tile.
    bf16x8 af2[2][4], bfr2[2][6];
#pragma unroll
    for (int ks = 0; ks < 2; ++ks) {
      const int ko = (ks * 32 + quad * 8) ^ swz;
#pragma unroll
      for (int f = 0; f < 4; ++f)
        af2[ks][f] = *(const bf16x8*)(Ab + (wr * 64 + f * 16 + l16) * 64 + ko);
#pragma unroll
      for (int g = 0; g < 6; ++g)
        bfr2[ks][g] = *(const bf16x8*)(Bb + (wc * 96 + g * 16 + l16) * 64 + ko);
    }
    asm volatile("s_waitcnt lgkmcnt(0)" ::: "memory");   // own frags in regs
    __builtin_amdgcn_s_barrier();                        // all waves done reading buf[cur]
    // buf[cur] is now free: issue tile kt+2 into it; its latency hides under MFMA.
    if (kt + 2 < NKT) STAGE(cur, kt + 2);
    __builtin_amdgcn_sched_barrier(0);                   // keep glds issue before MFMAs

    __builtin_amdgcn_s_setprio(1);
#pragma unroll
    for (int ks = 0; ks < 2; ++ks)
#pragma unroll
      for (int f = 0; f < 4; ++f)
#pragma unroll
        for (int g = 0; g < 6; ++g)
          acc[f][g] = __builtin_amdgcn_mfma_f32_16x16x32_bf16(
              af2[ks][f], bfr2[ks][g], acc[f][g], 0, 0, 0);
    __builtin_amdgcn_s_setprio(0);
  }

  // ---- Epilogue A: rope in regs; v -> HBM; q_rot/k_rot -> reused LDS ----
  // After the final lgkmcnt(0)+barrier no wave reads the GEMM LDS again -> reuse.
  // q_lds = lds[0][0..8191] (128 rows x 64), k_lds = lds[0][8192..16383].
  ushort* qk_lds = &lds[0][0];
#pragma unroll
  for (int g = 0; g < 6; ++g) {
    const int ncol = wc * 96 + g * 16;            // fused col base of this frag
    const int z = ncol >> 6;                      // 0=q, 1=k, 2=v
    const int el = (ncol & 63) + l16;             // e within slice (0..63)
    const int eg = e0 + el;                       // global e
    if (z < 2) {
      // theta = 10000^(-2*(i-1)/2048), i = e>>1  (keeps the reference's i-1 "bug")
      const float theta = exp2f(-0.012976281620653759f * ((float)(eg >> 1) - 1.0f));
      float cs[4], sn[4];
#pragma unroll
      for (int r = 0; r < 4; ++r)
        __sincosf((float)(quad * 4 + r) * theta, &sn[r], &cs[r]);
#pragma unroll
      for (int f = 0; f < 4; ++f) {
#pragma unroll
        for (int r = 0; r < 4; ++r) {
          float v = acc[f][g][r];
          float p = __shfl_xor(v, 1);        // partner along e (pair 2i / 2i+1)
          float o = (eg & 1) ? (v * cs[r] - p * sn[r])
                             : (v * cs[r] + p * sn[r]);
          const int row = wr * 64 + f * 16 + quad * 4 + r;      // 0..127
          const int colw = el ^ ((row & 7) << 3);               // write-side swizzle
          qk_lds[z * 8192 + row * 64 + colw] = f32_to_bf16(o);
        }
      }
    } else {
      // v: no rope, straight to HBM (bf16)
#pragma unroll
      for (int f = 0; f < 4; ++f) {
        const size_t rbase = (size_t)(m0 + wr * 64 + f * 16 + quad * 4) * D;
#pragma unroll
        for (int r = 0; r < 4; ++r)
          Ov[rbase + (size_t)r * D + eg] = f32_to_bf16(acc[f][g][r]);
      }
    }
  }
  __syncthreads();

  // ---- Epilogue B: per-batch partial scores S = q_rot @ k_rot^T over this e-slice ----
  // Wave w handles local batches 2w, 2w+1. Both operand frags: lane l16 = row-within-
  // batch, elements along e (same discipline as the verified stage-2 QK^T).
  const int gb0 = (m0 >> 4);                      // global batch base (8 per block)
#pragma unroll
  for (int bb = 0; bb < 2; ++bb) {
    const int bi = wave * 2 + bb;                 // local batch 0..7
    const int row = bi * 16 + l16;                // row&7 == l16&7 (bi*16 % 8 == 0)
    f32x4 s = {0.f, 0.f, 0.f, 0.f};
#pragma unroll
    for (int ks = 0; ks < 2; ++ks) {
      const int ko = (ks * 32 + quad * 8) ^ swz;
      bf16x8 aq = *(const bf16x8*)(qk_lds + row * 64 + ko);
      bf16x8 bk = *(const bf16x8*)(qk_lds + 8192 + row * 64 + ko);
      s = __builtin_amdgcn_mfma_f32_16x16x32_bf16(aq, bk, s, 0, 0, 0);
    }
    // C layout: col(m2) = l16, row(m1) = quad*4 + r. One slice per (eb, batch).
    float* sp = Sp + ((size_t)(eb * NBATCH + gb0 + bi) << 8);
#pragma unroll
    for (int r = 0; r < 4; ++r)
      sp[(quad * 4 + r) * 16 + l16] = s[r];
  }
}

// ---------------- Stage 2: softmax + P@V ----------------
// grid 256 (one block per batch), block 256.
__global__ __launch_bounds__(256) void rope_attention(
    const float* __restrict__ Sp, const ushort* __restrict__ V,
    const void* __restrict__ Wqr, void* __restrict__ OutRaw) {
  __shared__ float at[16][16];
  const bool f32out = detect_f32((const ushort*)Wqr);
  const int b = blockIdx.x;
  const int t = threadIdx.x;

  {
    const int m = t >> 4, n = t & 15;
    float s = 0.f;
#pragma unroll
    for (int ebi = 0; ebi < 32; ++ebi)
      s += Sp[((size_t)(ebi * NBATCH + b) << 8) + t];
    s *= 0.02209708691207961f;                    // 1/sqrt(2048)
    float mx = s;
#pragma unroll
    for (int off = 8; off; off >>= 1) mx = fmaxf(mx, __shfl_xor(mx, off, 16));
    float e = __expf(s - mx);
    float sum = e;
#pragma unroll
    for (int off = 8; off; off >>= 1) sum += __shfl_xor(sum, off, 16);
    at[m][n] = e / sum;
  }
  __syncthreads();

  // PV: thread t owns 8 contiguous e-cols; v held in regs as packed bf16.
  const ushort* Vb = V + (size_t)b * (SEQLEN * D);
  const int e0 = t * 8;
  uint4 vr[16];
#pragma unroll
  for (int n = 0; n < 16; ++n)
    vr[n] = *(const uint4*)(Vb + n * D + e0);

  for (int m = 0; m < 16; ++m) {
    float av[8] = {0.f, 0.f, 0.f, 0.f, 0.f, 0.f, 0.f, 0.f};
#pragma unroll
    for (int n = 0; n < 16; ++n) {
      const float a = at[m][n];
      const uint4 u = vr[n];
      av[0] = fmaf(a, bf16lo_to_f32(u.x), av[0]);
      av[1] = fmaf(a, bf16hi_to_f32(u.x), av[1]);
      av[2] = fmaf(a, bf16lo_to_f32(u.y), av[2]);
      av[3] = fmaf(a, bf16hi_to_f32(u.y), av[3]);
      av[4] = fmaf(a, bf16lo_to_f32(u.z), av[4]);
      av[5] = fmaf(a, bf16hi_to_f32(u.z), av[5]);
      av[6] = fmaf(a, bf16lo_to_f32(u.w), av[6]);
      av[7] = fmaf(a, bf16hi_to_f32(u.w), av[7]);
    }
    if (f32out) {
      float* Ob = (float*)OutRaw + (size_t)b * (SEQLEN * D) + m * D + e0;
      float4 o0 = {av[0], av[1], av[2], av[3]};
      float4 o1 = {av[4], av[5], av[6], av[7]};
      ((float4*)Ob)[0] = o0;
      ((float4*)Ob)[1] = o1;
    } else {
      uint4 o;
      o.x = (unsigned)f32_to_bf16(av[0]) | ((unsigned)f32_to_bf16(av[1]) << 16);
      o.y = (unsigned)f32_to_bf16(av[2]) | ((unsigned)f32_to_bf16(av[3]) << 16);
      o.z = (unsigned)f32_to_bf16(av[4]) | ((unsigned)f32_to_bf16(av[5]) << 16);
      o.w = (unsigned)f32_to_bf16(av[6]) | ((unsigned)f32_to_bf16(av[7]) << 16);
      *(uint4*)((ushort*)OutRaw + (size_t)b * (SEQLEN * D) + m * D + e0) = o;
    }
  }
}

extern "C" void kernel_launch(void* const* d_in, const int* in_sizes, int n_in,
                              void* d_out, int out_size, void* d_ws, size_t ws_size,
                              hipStream_t stream) {
  const void* x  = d_in[0];
  const void* wq = d_in[1];
  const void* wk = d_in[2];
  const void* wv = d_in[3];
  ushort* ws = (ushort*)d_ws;
  // ws layout (ushort units): xb | wqb | wkb | wvb | v | Sp(f32 x 2M)
  ushort* xb  = ws;
  ushort* wqb = ws + NX;
  ushort* wkb = ws + NX + NW;
  ushort* wvb = ws + NX + 2 * (size_t)NW;
  ushort* v   = ws + NX + 3 * (size_t)NW;
  float*  Sp  = (float*)(ws + 2 * (size_t)NX + 3 * (size_t)NW);

  convert_inputs<<<1536, 256, 0, stream>>>(x, wq, wk, wv, xb, wqb, wkb, wvb);
  qkv_rope_gemm<<<dim3(1024), 256, 0, stream>>>(x, wq, wk, wv, xb, wqb, wkb, wvb, v, Sp);
  rope_attention<<<NBATCH, 256, 0, stream>>>(Sp, v, wq, (ushort*)d_out);
}